// Round 1
// baseline (1878.908 us; speedup 1.0000x reference)
//
#include <hip/hip_runtime.h>
#include <hip/hip_fp16.h>
#include <cstdint>
#include <cstddef>

namespace {

constexpr int kB  = 16;
constexpr int kC  = 512;
constexpr int kCQ = 64;    // C/8
constexpr int kCV = 256;   // C/2
constexpr int kN  = 4096;  // 64*64 spatial
constexpr int kM  = 1024;  // 32*32 pooled spatial

// ---------------------------------------------------------------------------
// Kernel 1: P = Wcat @ X_b  (1x1 convs), fused 2x2 maxpool for k/v rows.
// Grid: (ntile=32, mtile=6, b=16). Block: 256.
// n-tile = 128 positions = image rows 2*nt and 2*nt+1 (64 cols each).
// mtile 0 -> f rows (wq), 1 -> g rows (wk, pooled), 2..5 -> h rows (wv, pooled)
// ---------------------------------------------------------------------------
__global__ __launch_bounds__(256)
void proj_pool_kernel(const float* __restrict__ x,
                      const float* __restrict__ wq,
                      const float* __restrict__ wk,
                      const float* __restrict__ wv,
                      float* __restrict__ f,   // [B][64][4096]
                      float* __restrict__ g,   // [B][64][1024]
                      float* __restrict__ h)   // [B][256][1024]
{
    const int nt  = blockIdx.x;   // 0..31
    const int mt  = blockIdx.y;   // 0..5
    const int b   = blockIdx.z;
    const int tid = threadIdx.x;

    __shared__ float As[64][36];    // pad 32 -> 36 (float4-aligned, bank-spread)
    __shared__ float Bs[32][132];   // pad 128 -> 132

    const float* A = (mt == 0) ? wq : (mt == 1) ? wk
                                   : (wv + (size_t)(mt - 2) * 64 * kC);
    const float* Xb = x + (size_t)b * kC * kN + nt * 128;

    const int ty = tid >> 4;     // 0..15 -> out rows ty*4..+3
    const int tx = tid & 15;     // 0..15 -> cols tx*4..+3 (row 2nt) and 64+tx*4..+3 (row 2nt+1)

    float acc[4][8];
#pragma unroll
    for (int i = 0; i < 4; ++i)
#pragma unroll
        for (int j = 0; j < 8; ++j) acc[i][j] = 0.f;

    const int arow = tid >> 2;          // 0..63
    const int acol = (tid & 3) * 8;     // 0,8,16,24
    const int brow = tid >> 3;          // 0..31
    const int bcol = (tid & 7) * 16;    // 0..112

    for (int k0 = 0; k0 < kC; k0 += 32) {
        // stage A 64x32
        {
            const float* ap = A + (size_t)arow * kC + k0 + acol;
            float4 a0 = *(const float4*)ap;
            float4 a1 = *(const float4*)(ap + 4);
            *(float4*)&As[arow][acol]     = a0;
            *(float4*)&As[arow][acol + 4] = a1;
        }
        // stage B 32x128
        {
            const float* bp = Xb + (size_t)(k0 + brow) * kN + bcol;
            float4 b0 = *(const float4*)(bp);
            float4 b1 = *(const float4*)(bp + 4);
            float4 b2 = *(const float4*)(bp + 8);
            float4 b3 = *(const float4*)(bp + 12);
            *(float4*)&Bs[brow][bcol]      = b0;
            *(float4*)&Bs[brow][bcol + 4]  = b1;
            *(float4*)&Bs[brow][bcol + 8]  = b2;
            *(float4*)&Bs[brow][bcol + 12] = b3;
        }
        __syncthreads();
#pragma unroll
        for (int k = 0; k < 32; ++k) {
            float av[4];
#pragma unroll
            for (int i = 0; i < 4; ++i) av[i] = As[ty * 4 + i][k];
            float4 bl = *(const float4*)&Bs[k][tx * 4];
            float4 br = *(const float4*)&Bs[k][64 + tx * 4];
            float bv[8] = {bl.x, bl.y, bl.z, bl.w, br.x, br.y, br.z, br.w};
#pragma unroll
            for (int i = 0; i < 4; ++i)
#pragma unroll
                for (int j = 0; j < 8; ++j) acc[i][j] += av[i] * bv[j];
        }
        __syncthreads();
    }

    if (mt == 0) {
        float* fb = f + (size_t)b * kCQ * kN + nt * 128;
#pragma unroll
        for (int i = 0; i < 4; ++i) {
            const int m = ty * 4 + i;
            float4 v0 = make_float4(acc[i][0], acc[i][1], acc[i][2], acc[i][3]);
            float4 v1 = make_float4(acc[i][4], acc[i][5], acc[i][6], acc[i][7]);
            *(float4*)(fb + (size_t)m * kN + tx * 4)      = v0;
            *(float4*)(fb + (size_t)m * kN + 64 + tx * 4) = v1;
        }
    } else {
        // 2x2 maxpool: cols j={0,1,4,5} -> wp=tx*2 ; j={2,3,6,7} -> wp=tx*2+1
        float* dst;
        int chbase, cstride;
        if (mt == 1) { dst = g; chbase = 0;              cstride = kCQ; }
        else         { dst = h; chbase = (mt - 2) * 64;  cstride = kCV; }
#pragma unroll
        for (int i = 0; i < 4; ++i) {
            const int ch = chbase + ty * 4 + i;
            float p0 = fmaxf(fmaxf(acc[i][0], acc[i][1]), fmaxf(acc[i][4], acc[i][5]));
            float p1 = fmaxf(fmaxf(acc[i][2], acc[i][3]), fmaxf(acc[i][6], acc[i][7]));
            const size_t base = (size_t)b * cstride * kM + (size_t)ch * kM + nt * 32;
            dst[base + tx * 2]     = p0;
            dst[base + tx * 2 + 1] = p1;
        }
    }
}

// ---------------------------------------------------------------------------
// Kernel 2: flash attention over pooled kv + fused wo projection + residual.
// Grid: (qtile=64, b=16). Block: 256. Each block: 64 queries, all 1024 m.
// ---------------------------------------------------------------------------
__global__ __launch_bounds__(256)
void attn_out_kernel(const float* __restrict__ f,
                     const float* __restrict__ g,
                     const float* __restrict__ h,
                     const float* __restrict__ wo,     // [512][256]
                     const float* __restrict__ x,
                     const float* __restrict__ gamma,
                     float* __restrict__ out)
{
    const int qt  = blockIdx.x;   // 0..63
    const int b   = blockIdx.y;
    const int tid = threadIdx.x;

    __shared__ union SMem {
        struct {
            float fs[64][68];     // f tile   [cq][q]       17408 B
            float gsps[64 * 36];  // g chunk [cq][m] stride 36 / p [q][m] stride 33 (9216 B)
            float hs[32][260];    // h chunk transposed [m][c]  33280 B
        } p1;
        struct {
            unsigned os[256][34]; // o tile f16-packed [c][q/2]  34816 B
            float wos[16][260];   // wo slab [k][oc']            16640 B
        } p2;
    } sm;
    __shared__ float s_rm[64];  // running row max
    __shared__ float s_rl[64];  // running row sum
    __shared__ float s_al[64];  // per-chunk alpha

    // ---- load f tile: fs[cq][q] ----
    {
        const float* fb = f + (size_t)b * kCQ * kN + qt * 64;
        const int col = (tid & 15) * 4;
#pragma unroll
        for (int j = 0; j < 4; ++j) {
            const int c = (tid >> 4) + j * 16;
            *(float4*)&sm.p1.fs[c][col] = *(const float4*)(fb + (size_t)c * kN + col);
        }
    }

    float o_acc[16][4];
#pragma unroll
    for (int i = 0; i < 16; ++i)
#pragma unroll
        for (int j = 0; j < 4; ++j) o_acc[i][j] = 0.f;

    const int tq  = tid >> 4;   // S phase: q rows tq*4..+3
    const int tm  = tid & 15;   //          m cols tm*2..+1
    const int tc  = tid >> 4;   // PV/GEMM2: c rows tc*16..+15
    const int tqq = tid & 15;   //           q cols tqq*4..+3

    for (int mi = 0; mi < 32; ++mi) {
        const int m0 = mi * 32;
        __syncthreads();   // prev chunk's PV reads done (covers fs load at mi==0)

        // ---- stage g chunk [64][32] and h chunk transposed [32][256] ----
        {
            const int mm = (tid & 7) * 4;
#pragma unroll
            for (int j = 0; j < 2; ++j) {
                const int c = (tid >> 3) + j * 32;
                *(float4*)&sm.p1.gsps[c * 36 + mm] =
                    *(const float4*)(g + (size_t)b * kCQ * kM + (size_t)c * kM + m0 + mm);
            }
#pragma unroll
            for (int j = 0; j < 8; ++j) {
                const int c = (tid >> 3) + j * 32;
                float4 hv = *(const float4*)(h + (size_t)b * kCV * kM + (size_t)c * kM + m0 + mm);
                sm.p1.hs[mm + 0][c] = hv.x;
                sm.p1.hs[mm + 1][c] = hv.y;
                sm.p1.hs[mm + 2][c] = hv.z;
                sm.p1.hs[mm + 3][c] = hv.w;
            }
        }
        __syncthreads();

        // ---- S = f^T g : each thread 4q x 2m, K=64 ----
        float sv[4][2] = {{0, 0}, {0, 0}, {0, 0}, {0, 0}};
#pragma unroll 8
        for (int k = 0; k < 64; ++k) {
            float4 av = *(const float4*)&sm.p1.fs[k][tq * 4];
            const float b0 = sm.p1.gsps[k * 36 + tm * 2];
            const float b1 = sm.p1.gsps[k * 36 + tm * 2 + 1];
            sv[0][0] += av.x * b0;  sv[0][1] += av.x * b1;
            sv[1][0] += av.y * b0;  sv[1][1] += av.y * b1;
            sv[2][0] += av.z * b0;  sv[2][1] += av.z * b1;
            sv[3][0] += av.w * b0;  sv[3][1] += av.w * b1;
        }

        // ---- online softmax (row lives in one wave; state in LDS) ----
        float pv_[4][2];
#pragma unroll
        for (int i = 0; i < 4; ++i) {
            const int q = tq * 4 + i;
            float cm = fmaxf(sv[i][0], sv[i][1]);
#pragma unroll
            for (int off = 1; off < 16; off <<= 1) cm = fmaxf(cm, __shfl_xor(cm, off, 64));
            const float old_m = (mi == 0) ? -3.0e38f : s_rm[q];
            const float new_m = fmaxf(old_m, cm);
            const float al    = __expf(old_m - new_m);
            const float p0 = __expf(sv[i][0] - new_m);
            const float p1 = __expf(sv[i][1] - new_m);
            float ps = p0 + p1;
#pragma unroll
            for (int off = 1; off < 16; off <<= 1) ps += __shfl_xor(ps, off, 64);
            if (tm == 0) {
                s_rm[q] = new_m;
                s_rl[q] = ((mi == 0) ? 0.f : s_rl[q]) * al + ps;
                s_al[q] = al;
            }
            pv_[i][0] = p0;
            pv_[i][1] = p1;
        }
        __syncthreads();   // everyone done reading gs; alphas visible after next barrier

        // ---- write p over gs region, stride 33 (scalar; bank-spread for PV reads) ----
#pragma unroll
        for (int i = 0; i < 4; ++i) {
            sm.p1.gsps[(tq * 4 + i) * 33 + tm * 2]     = pv_[i][0];
            sm.p1.gsps[(tq * 4 + i) * 33 + tm * 2 + 1] = pv_[i][1];
        }
        __syncthreads();

        // ---- PV: o[c][q] = alpha*o + h_chunk @ p^T ----
        float al4[4];
#pragma unroll
        for (int j = 0; j < 4; ++j) al4[j] = s_al[tqq * 4 + j];
#pragma unroll
        for (int i = 0; i < 16; ++i)
#pragma unroll
            for (int j = 0; j < 4; ++j) o_acc[i][j] *= al4[j];
#pragma unroll 4
        for (int m = 0; m < 32; ++m) {
            float4 h0 = *(const float4*)&sm.p1.hs[m][tc * 16 + 0];
            float4 h1 = *(const float4*)&sm.p1.hs[m][tc * 16 + 4];
            float4 h2 = *(const float4*)&sm.p1.hs[m][tc * 16 + 8];
            float4 h3 = *(const float4*)&sm.p1.hs[m][tc * 16 + 12];
            float hv[16] = {h0.x, h0.y, h0.z, h0.w, h1.x, h1.y, h1.z, h1.w,
                            h2.x, h2.y, h2.z, h2.w, h3.x, h3.y, h3.z, h3.w};
            float pj[4];
#pragma unroll
            for (int j = 0; j < 4; ++j) pj[j] = sm.p1.gsps[(tqq * 4 + j) * 33 + m];
#pragma unroll
            for (int i = 0; i < 16; ++i)
#pragma unroll
                for (int j = 0; j < 4; ++j) o_acc[i][j] += hv[i] * pj[j];
        }
    }

    __syncthreads();   // final PV reads done -> safe to repurpose LDS as phase 2

    // ---- normalize, pack o into LDS as f16 pairs: os[c][q/2] ----
    {
        float inv4[4];
#pragma unroll
        for (int j = 0; j < 4; ++j) inv4[j] = 1.0f / s_rl[tqq * 4 + j];
#pragma unroll
        for (int i = 0; i < 16; ++i) {
            const int c = tc * 16 + i;
#pragma unroll
            for (int jp = 0; jp < 2; ++jp) {
                const float v0 = o_acc[i][2 * jp]     * inv4[2 * jp];
                const float v1 = o_acc[i][2 * jp + 1] * inv4[2 * jp + 1];
                const __half hh0 = __float2half(v0);
                const __half hh1 = __float2half(v1);
                const unsigned u = (unsigned)__half_as_ushort(hh0) |
                                   ((unsigned)__half_as_ushort(hh1) << 16);
                sm.p2.os[c][tqq * 2 + jp] = u;
            }
        }
    }

    // ---- GEMM2: out = gamma * wo @ o + x  (512 oc in two halves of 256) ----
    const float gma = gamma[0];
    for (int half = 0; half < 2; ++half) {
        float acc2[16][4];
#pragma unroll
        for (int i = 0; i < 16; ++i)
#pragma unroll
            for (int j = 0; j < 4; ++j) acc2[i][j] = 0.f;

        for (int c0 = 0; c0 < 256; c0 += 16) {
            __syncthreads();   // prev slab reads done (first iter: os writes done)
            {
                const int kk = (tid & 3) * 4;
#pragma unroll
                for (int j = 0; j < 4; ++j) {
                    const int ocp = (tid >> 2) + j * 64;
                    float4 wv4 = *(const float4*)(wo + (size_t)(half * 256 + ocp) * 256 + c0 + kk);
                    sm.p2.wos[kk + 0][ocp] = wv4.x;
                    sm.p2.wos[kk + 1][ocp] = wv4.y;
                    sm.p2.wos[kk + 2][ocp] = wv4.z;
                    sm.p2.wos[kk + 3][ocp] = wv4.w;
                }
            }
            __syncthreads();
#pragma unroll
            for (int kk2 = 0; kk2 < 16; ++kk2) {
                float4 a0 = *(const float4*)&sm.p2.wos[kk2][tc * 16 + 0];
                float4 a1 = *(const float4*)&sm.p2.wos[kk2][tc * 16 + 4];
                float4 a2 = *(const float4*)&sm.p2.wos[kk2][tc * 16 + 8];
                float4 a3 = *(const float4*)&sm.p2.wos[kk2][tc * 16 + 12];
                const unsigned u0 = sm.p2.os[c0 + kk2][tqq * 2];
                const unsigned u1 = sm.p2.os[c0 + kk2][tqq * 2 + 1];
                float bv[4];
                bv[0] = __half2float(__ushort_as_half((unsigned short)(u0 & 0xffffu)));
                bv[1] = __half2float(__ushort_as_half((unsigned short)(u0 >> 16)));
                bv[2] = __half2float(__ushort_as_half((unsigned short)(u1 & 0xffffu)));
                bv[3] = __half2float(__ushort_as_half((unsigned short)(u1 >> 16)));
                float av[16] = {a0.x, a0.y, a0.z, a0.w, a1.x, a1.y, a1.z, a1.w,
                                a2.x, a2.y, a2.z, a2.w, a3.x, a3.y, a3.z, a3.w};
#pragma unroll
                for (int i = 0; i < 16; ++i)
#pragma unroll
                    for (int j = 0; j < 4; ++j) acc2[i][j] += av[i] * bv[j];
            }
        }

        // epilogue: gamma * acc + x, float4 per oc row
        const int n0 = qt * 64 + tqq * 4;
#pragma unroll
        for (int i = 0; i < 16; ++i) {
            const int oc = half * 256 + tc * 16 + i;
            const size_t idx = (size_t)b * kC * kN + (size_t)oc * kN + n0;
            const float4 xr = *(const float4*)(x + idx);
            float4 ov;
            ov.x = gma * acc2[i][0] + xr.x;
            ov.y = gma * acc2[i][1] + xr.y;
            ov.z = gma * acc2[i][2] + xr.z;
            ov.w = gma * acc2[i][3] + xr.w;
            *(float4*)(out + idx) = ov;
        }
    }
}

}  // namespace

extern "C" void kernel_launch(void* const* d_in, const int* in_sizes, int n_in,
                              void* d_out, int out_size, void* d_ws, size_t ws_size,
                              hipStream_t stream) {
    const float* x     = (const float*)d_in[0];
    const float* wq    = (const float*)d_in[1];
    const float* wk    = (const float*)d_in[2];
    const float* wv    = (const float*)d_in[3];
    const float* wo    = (const float*)d_in[4];
    const float* gamma = (const float*)d_in[5];
    float* out = (float*)d_out;

    // workspace: f [16][64][4096], g [16][64][1024], h [16][256][1024]
    float* f = (float*)d_ws;
    float* g = f + (size_t)kB * kCQ * kN;   // +4,194,304
    float* h = g + (size_t)kB * kCQ * kM;   // +1,048,576  (total 36 MB)

    hipLaunchKernelGGL(proj_pool_kernel, dim3(32, 6, kB), dim3(256), 0, stream,
                       x, wq, wk, wv, f, g, h);
    hipLaunchKernelGGL(attn_out_kernel, dim3(64, kB), dim3(256), 0, stream,
                       f, g, h, wo, x, gamma, out);
}

// Round 2
// 801.514 us; speedup vs baseline: 2.3442x; 2.3442x over previous
//
#include <hip/hip_runtime.h>
#include <cstdint>
#include <cstddef>

namespace {

constexpr int kB  = 16;
constexpr int kC  = 512;
constexpr int kCQ = 64;    // C/8
constexpr int kCV = 256;   // C/2
constexpr int kN  = 4096;  // 64*64 spatial
constexpr int kM  = 1024;  // 32*32 pooled spatial

typedef _Float16 f16;
typedef _Float16 f16x8 __attribute__((ext_vector_type(8)));
typedef float    f32x4 __attribute__((ext_vector_type(4)));

// ---------------------------------------------------------------------------
// Kernel 0: woh = (f16)(gamma * wo)   [512][256]
// ---------------------------------------------------------------------------
__global__ __launch_bounds__(256)
void convert_wo_kernel(const float* __restrict__ wo, const float* __restrict__ gamma,
                       f16* __restrict__ woh)
{
    const int i = (blockIdx.x * 256 + threadIdx.x) * 4;
    const float g = gamma[0];
    float4 v = *(const float4*)(wo + i);
    union { f16 h4[4]; uint2 u; } pk;
    pk.h4[0] = (f16)(g * v.x);
    pk.h4[1] = (f16)(g * v.y);
    pk.h4[2] = (f16)(g * v.z);
    pk.h4[3] = (f16)(g * v.w);
    *(uint2*)(woh + i) = pk.u;
}

// ---------------------------------------------------------------------------
// Kernel 1: P = Wcat @ X_b (1x1 convs), fused 2x2 maxpool, f16 outputs in
// MFMA-friendly layouts: fT [B][n][64], gT [B][m][64], h [B][256][m].
// Grid: (ntile=32, mtile=6, b=16). Block: 256. fp32 compute (unchanged core).
// ---------------------------------------------------------------------------
__global__ __launch_bounds__(256)
void proj_pool_kernel(const float* __restrict__ x,
                      const float* __restrict__ wq,
                      const float* __restrict__ wk,
                      const float* __restrict__ wv,
                      f16* __restrict__ fT,   // [B][4096][64]
                      f16* __restrict__ gT,   // [B][1024][64]
                      f16* __restrict__ h)    // [B][256][1024]
{
    const int nt  = blockIdx.x;   // 0..31
    const int mt  = blockIdx.y;   // 0..5
    const int b   = blockIdx.z;
    const int tid = threadIdx.x;

    __shared__ float As[64][36];
    __shared__ float Bs[32][132];

    const float* A = (mt == 0) ? wq : (mt == 1) ? wk
                                   : (wv + (size_t)(mt - 2) * 64 * kC);
    const float* Xb = x + (size_t)b * kC * kN + nt * 128;

    const int ty = tid >> 4;     // out-channel group: ch = ty*4..+3
    const int tx = tid & 15;     // col group

    float acc[4][8];
#pragma unroll
    for (int i = 0; i < 4; ++i)
#pragma unroll
        for (int j = 0; j < 8; ++j) acc[i][j] = 0.f;

    const int arow = tid >> 2;
    const int acol = (tid & 3) * 8;
    const int brow = tid >> 3;
    const int bcol = (tid & 7) * 16;

    for (int k0 = 0; k0 < kC; k0 += 32) {
        {
            const float* ap = A + (size_t)arow * kC + k0 + acol;
            float4 a0 = *(const float4*)ap;
            float4 a1 = *(const float4*)(ap + 4);
            *(float4*)&As[arow][acol]     = a0;
            *(float4*)&As[arow][acol + 4] = a1;
        }
        {
            const float* bp = Xb + (size_t)(k0 + brow) * kN + bcol;
            float4 b0 = *(const float4*)(bp);
            float4 b1 = *(const float4*)(bp + 4);
            float4 b2 = *(const float4*)(bp + 8);
            float4 b3 = *(const float4*)(bp + 12);
            *(float4*)&Bs[brow][bcol]      = b0;
            *(float4*)&Bs[brow][bcol + 4]  = b1;
            *(float4*)&Bs[brow][bcol + 8]  = b2;
            *(float4*)&Bs[brow][bcol + 12] = b3;
        }
        __syncthreads();
#pragma unroll
        for (int k = 0; k < 32; ++k) {
            float av[4];
#pragma unroll
            for (int i = 0; i < 4; ++i) av[i] = As[ty * 4 + i][k];
            float4 bl = *(const float4*)&Bs[k][tx * 4];
            float4 br = *(const float4*)&Bs[k][64 + tx * 4];
            float bv[8] = {bl.x, bl.y, bl.z, bl.w, br.x, br.y, br.z, br.w};
#pragma unroll
            for (int i = 0; i < 4; ++i)
#pragma unroll
                for (int j = 0; j < 8; ++j) acc[i][j] += av[i] * bv[j];
        }
        __syncthreads();
    }

    if (mt == 0) {
        // fT[n][ch]: per col j, thread's 4 channels are consecutive -> 8B stores
        f16* fb = fT + (size_t)b * kN * kCQ;
#pragma unroll
        for (int j = 0; j < 8; ++j) {
            const int n = nt * 128 + (j >> 2) * 64 + tx * 4 + (j & 3);
            union { f16 h4[4]; uint2 u; } pk;
#pragma unroll
            for (int i = 0; i < 4; ++i) pk.h4[i] = (f16)acc[i][j];
            *(uint2*)(fb + (size_t)n * kCQ + ty * 4) = pk.u;
        }
    } else if (mt == 1) {
        // pooled -> gT[m][ch]
        f16* gb = gT + (size_t)b * kM * kCQ;
        const int mp = nt * 32 + tx * 2;
        union { f16 h4[4]; uint2 u; } pk0, pk1;
#pragma unroll
        for (int i = 0; i < 4; ++i) {
            float p0 = fmaxf(fmaxf(acc[i][0], acc[i][1]), fmaxf(acc[i][4], acc[i][5]));
            float p1 = fmaxf(fmaxf(acc[i][2], acc[i][3]), fmaxf(acc[i][6], acc[i][7]));
            pk0.h4[i] = (f16)p0;
            pk1.h4[i] = (f16)p1;
        }
        *(uint2*)(gb + (size_t)mp * kCQ + ty * 4)       = pk0.u;
        *(uint2*)(gb + (size_t)(mp + 1) * kCQ + ty * 4) = pk1.u;
    } else {
        // pooled -> h[ch][m]
        const int chbase = (mt - 2) * 64;
#pragma unroll
        for (int i = 0; i < 4; ++i) {
            const int ch = chbase + ty * 4 + i;
            float p0 = fmaxf(fmaxf(acc[i][0], acc[i][1]), fmaxf(acc[i][4], acc[i][5]));
            float p1 = fmaxf(fmaxf(acc[i][2], acc[i][3]), fmaxf(acc[i][6], acc[i][7]));
            union { f16 h2[2]; unsigned u; } pk;
            pk.h2[0] = (f16)p0;
            pk.h2[1] = (f16)p1;
            *(unsigned*)(h + ((size_t)b * kCV + ch) * kM + nt * 32 + tx * 2) = pk.u;
        }
    }
}

// ---------------------------------------------------------------------------
// Kernel 2: MFMA flash attention + fused wo GEMM + residual.
// Grid: (qtile=64, b=16). Block: 256 = 4 waves. Wave w owns queries
// q = qt*64 + w*16 .. +15 end-to-end (S rows, P rows, PV cols, GEMM2 cols) --
// no cross-wave dependencies except tile staging (2 barriers/chunk).
// MFMA 16x16x32 f16 layouts: A[m=lane&15][k=quad*8+j], B[k=quad*8+j][n=lane&15],
// D[row=quad*4+reg][col=lane&15].
// ---------------------------------------------------------------------------
__global__ __launch_bounds__(256, 3)
void attn_out_kernel(const f16* __restrict__ fT,
                     const f16* __restrict__ gT,
                     const f16* __restrict__ hmat,
                     const f16* __restrict__ woh,   // gamma*wo, f16 [512][256]
                     const float* __restrict__ x,
                     float* __restrict__ out)
{
    const int qt   = blockIdx.x;
    const int b    = blockIdx.y;
    const int tid  = threadIdx.x;
    const int w    = tid >> 6;
    const int lane = tid & 63;
    const int quad = lane >> 4;
    const int lq   = lane & 15;

    __shared__ union alignas(16) SMem {
        struct {
            f16   fsT[64 * 72];    // [q][ch], pad 72: bank stride 4 -> 2-way (free)
            f16   gsT[32 * 64];    // [m][ch], XOR-swizzled 16B units
            f16   hs[256 * 40];    // [c][m-chunk], pad 40: bank stride 20 -> 2-way
            f16   ps[64 * 40];     // [q][m-chunk], pad 40
            float al[64];          // per-q alpha (this chunk)
            float rl[64];          // per-q final l
        } p1;                      // 39424 B
        struct {
            f16 osT[4 * 16 * 264]; // [q-local][c], pad 264 per row
            f16 wos[256 * 40];     // [oc'][k-slab], pad 40
        } p2;                      // 54272 B
    } sm;

    // ---- stage fsT [64 q][64 ch] (8 KB) ----
    {
        const f16* fb = fT + ((size_t)b * kN + qt * 64) * kCQ;
#pragma unroll
        for (int p = 0; p < 2; ++p) {
            const int unit = tid + p * 256;
            const int q = unit >> 3, u = unit & 7;
            *(uint4*)&sm.p1.fsT[q * 72 + u * 8] = *(const uint4*)(fb + q * 64 + u * 8);
        }
    }
    __syncthreads();

    // loop-invariant A-frags of f (q = w*16+lq, ch = kb*32 + quad*8 + j)
    const f16x8 af0 = *(const f16x8*)&sm.p1.fsT[(w * 16 + lq) * 72 + quad * 8];
    const f16x8 af1 = *(const f16x8*)&sm.p1.fsT[(w * 16 + lq) * 72 + 32 + quad * 8];

    float m_run[4] = {-3.0e38f, -3.0e38f, -3.0e38f, -3.0e38f};
    float l_run[4] = {0.f, 0.f, 0.f, 0.f};
    f32x4 o_acc[16];
#pragma unroll
    for (int ci = 0; ci < 16; ++ci) o_acc[ci] = {0.f, 0.f, 0.f, 0.f};

    const f16* gTb = gT + (size_t)b * kM * kCQ;
    const f16* hb  = hmat + (size_t)b * kCV * kM;

    for (int mi = 0; mi < 32; ++mi) {
        const int m0 = mi * 32;
        __syncthreads();   // prior chunk's PV reads of hs done

        // ---- stage gsT [32 m][64 ch], XOR-swizzle 16B units ----
        {
            const int m = tid >> 3, su = tid & 7;
            const int gu = su ^ (m & 7);
            *(uint4*)&sm.p1.gsT[m * 64 + su * 8] =
                *(const uint4*)(gTb + (size_t)(m0 + m) * kCQ + gu * 8);
        }
        // ---- stage hs [256 c][32 m] ----
#pragma unroll
        for (int p = 0; p < 4; ++p) {
            const int c = (tid >> 2) + p * 64, u = tid & 3;
            *(uint4*)&sm.p1.hs[c * 40 + u * 8] =
                *(const uint4*)(hb + (size_t)c * kM + m0 + u * 8);
        }
        __syncthreads();

        // ---- S = f^T g : wave w -> 16q x 32m, K=64 ----
        const int mr0 = lq, mr1 = 16 + lq;
        const f16x8 bg00 = *(const f16x8*)&sm.p1.gsT[mr0 * 64 + ((quad)     ^ (mr0 & 7)) * 8];
        const f16x8 bg01 = *(const f16x8*)&sm.p1.gsT[mr0 * 64 + ((4 + quad) ^ (mr0 & 7)) * 8];
        const f16x8 bg10 = *(const f16x8*)&sm.p1.gsT[mr1 * 64 + ((quad)     ^ (mr1 & 7)) * 8];
        const f16x8 bg11 = *(const f16x8*)&sm.p1.gsT[mr1 * 64 + ((4 + quad) ^ (mr1 & 7)) * 8];
        f32x4 s0 = {0.f, 0.f, 0.f, 0.f}, s1 = {0.f, 0.f, 0.f, 0.f};
        s0 = __builtin_amdgcn_mfma_f32_16x16x32_f16(af0, bg00, s0, 0, 0, 0);
        s0 = __builtin_amdgcn_mfma_f32_16x16x32_f16(af1, bg01, s0, 0, 0, 0);
        s1 = __builtin_amdgcn_mfma_f32_16x16x32_f16(af0, bg10, s1, 0, 0, 0);
        s1 = __builtin_amdgcn_mfma_f32_16x16x32_f16(af1, bg11, s1, 0, 0, 0);

        // ---- online softmax: row q = w*16 + quad*4 + r lives in this quad ----
#pragma unroll
        for (int r = 0; r < 4; ++r) {
            float cm = fmaxf(s0[r], s1[r]);
            cm = fmaxf(cm, __shfl_xor(cm, 1, 64));
            cm = fmaxf(cm, __shfl_xor(cm, 2, 64));
            cm = fmaxf(cm, __shfl_xor(cm, 4, 64));
            cm = fmaxf(cm, __shfl_xor(cm, 8, 64));
            const float nm = fmaxf(m_run[r], cm);
            const float al = __expf(m_run[r] - nm);   // mi==0: exp(-huge)=0
            const float p0 = __expf(s0[r] - nm);
            const float p1 = __expf(s1[r] - nm);
            float psum = p0 + p1;
            psum += __shfl_xor(psum, 1, 64);
            psum += __shfl_xor(psum, 2, 64);
            psum += __shfl_xor(psum, 4, 64);
            psum += __shfl_xor(psum, 8, 64);
            m_run[r] = nm;
            l_run[r] = l_run[r] * al + psum;
            if (lq == 0) sm.p1.al[w * 16 + quad * 4 + r] = al;
            sm.p1.ps[(w * 16 + quad * 4 + r) * 40 + lq]      = (f16)p0;
            sm.p1.ps[(w * 16 + quad * 4 + r) * 40 + 16 + lq] = (f16)p1;
        }

        // ---- PV: o[c][q] = alpha*o + h @ P^T  (wave-local ps/al, in-order LDS) ----
        const float alv = sm.p1.al[w * 16 + lq];
        const f16x8 bp  = *(const f16x8*)&sm.p1.ps[(w * 16 + lq) * 40 + quad * 8];
#pragma unroll
        for (int ci = 0; ci < 16; ++ci) {
            const f16x8 ha = *(const f16x8*)&sm.p1.hs[(ci * 16 + lq) * 40 + quad * 8];
            o_acc[ci] *= alv;
            o_acc[ci] = __builtin_amdgcn_mfma_f32_16x16x32_f16(ha, bp, o_acc[ci], 0, 0, 0);
        }
    }

    // ---- normalize; o -> LDS as f16 osT[q-local][c] ----
    if (lq == 0) {
#pragma unroll
        for (int r = 0; r < 4; ++r) sm.p1.rl[w * 16 + quad * 4 + r] = l_run[r];
    }
    const float inv = 1.0f / sm.p1.rl[w * 16 + lq];   // read BEFORE clobber barrier
    __syncthreads();
#pragma unroll
    for (int ci = 0; ci < 16; ++ci)
#pragma unroll
        for (int r = 0; r < 4; ++r)
            sm.p2.osT[(w * 16 + lq) * 264 + ci * 16 + quad * 4 + r] =
                (f16)(o_acc[ci][r] * inv);
    __syncthreads();

    // ---- GEMM2: out = woh @ o + x  (512 oc in 2 halves; K=256 in 8 slabs) ----
    for (int half = 0; half < 2; ++half) {
        f32x4 acc2[16];
#pragma unroll
        for (int os = 0; os < 16; ++os) acc2[os] = {0.f, 0.f, 0.f, 0.f};

        for (int ck = 0; ck < 8; ++ck) {
            __syncthreads();   // prev slab reads done
#pragma unroll
            for (int p = 0; p < 4; ++p) {
                const int oc = (tid >> 2) + p * 64, u = tid & 3;
                *(uint4*)&sm.p2.wos[oc * 40 + u * 8] =
                    *(const uint4*)(woh + (size_t)(half * 256 + oc) * 256 + ck * 32 + u * 8);
            }
            __syncthreads();
            const f16x8 bo = *(const f16x8*)&sm.p2.osT[(w * 16 + lq) * 264 + ck * 32 + quad * 8];
#pragma unroll
            for (int os = 0; os < 16; ++os) {
                const f16x8 wa = *(const f16x8*)&sm.p2.wos[(os * 16 + lq) * 40 + quad * 8];
                acc2[os] = __builtin_amdgcn_mfma_f32_16x16x32_f16(wa, bo, acc2[os], 0, 0, 0);
            }
        }

        const int n0 = qt * 64 + w * 16 + lq;
#pragma unroll
        for (int os = 0; os < 16; ++os) {
#pragma unroll
            for (int r = 0; r < 4; ++r) {
                const int oc = half * 256 + os * 16 + quad * 4 + r;
                const size_t idx = ((size_t)b * kC + oc) * (size_t)kN + n0;
                out[idx] = acc2[os][r] + x[idx];
            }
        }
    }
}

}  // namespace

extern "C" void kernel_launch(void* const* d_in, const int* in_sizes, int n_in,
                              void* d_out, int out_size, void* d_ws, size_t ws_size,
                              hipStream_t stream) {
    const float* x     = (const float*)d_in[0];
    const float* wq    = (const float*)d_in[1];
    const float* wk    = (const float*)d_in[2];
    const float* wv    = (const float*)d_in[3];
    const float* wo    = (const float*)d_in[4];
    const float* gamma = (const float*)d_in[5];
    float* out = (float*)d_out;

    // f16 workspace: fT [16][4096][64], gT [16][1024][64], h [16][256][1024],
    // woh [512][256]  -> 19.1 MB total
    f16* fT  = (f16*)d_ws;
    f16* gT  = fT + (size_t)kB * kN * kCQ;    // +4,194,304 el
    f16* hw  = gT + (size_t)kB * kM * kCQ;    // +1,048,576 el
    f16* woh = hw + (size_t)kB * kCV * kM;    // +4,194,304 el

    hipLaunchKernelGGL(convert_wo_kernel, dim3(128), dim3(256), 0, stream,
                       wo, gamma, woh);
    hipLaunchKernelGGL(proj_pool_kernel, dim3(32, 6, kB), dim3(256), 0, stream,
                       x, wq, wk, wv, fT, gT, hw);
    hipLaunchKernelGGL(attn_out_kernel, dim3(64, kB), dim3(256), 0, stream,
                       fT, gT, hw, woh, x, out);
}